// Round 10
// baseline (207.094 us; speedup 1.0000x reference)
//
#include <hip/hip_runtime.h>
#include <hip/hip_bf16.h>
#include <math.h>
#include <stddef.h>

#define BN 131072
#define CN 40
#define NTOT (BN * CN)
#define MASKW (BN / 64)   // fallback path only
#define NBLK 1024         // k_fuse grid
#define NFIN 2048         // k_final grid
#define NCHUNK 8          // selection chunks per column
#define CROWS (BN / NCHUNK)   // 16384 rows per chunk

// Workspace. memset zeroes [0 .. offsetof(u)] = acc+done+ghist0.
// u region lifetimes: fuse writes parts -> paramsA reads -> h0 zeroes g.h1/g.h2
// -> h1/h2 atomically accumulate. mask member is for the fallback path only.
struct Ws {
    double acc;
    unsigned done;
    unsigned pad0;
    unsigned ghist0[CN][2048];          // L0 hist: digit = mk>>19
    union {
        struct { unsigned h1[CN][4096]; unsigned h2[CN][4096]; } g;
        struct { float lpart[CN][NBLK]; int ppart[CN][NBLK]; } parts;
        unsigned long long mask[CN][MASKW];
    } u;
    double lossc[CN];
    int    posc[CN];
    float drate[CN];
    float majl[CN];
    float minl[CN];
    float w_hard[CN];
    float w_easy[CN];
    int   hardf[CN];
    int   kdrop[CN];
    int   minpos[CN];
    unsigned mkT[CN];                   // threshold g-bits
    unsigned rowT[CN];                  // threshold row (drop row <= rowT at mk==mkT)
    int      en[CN];                    // drop-enable per column
    unsigned keys[CN][BN];              // transposed packed (g_bits<<1)|t
};

__device__ __forceinline__ float bce_f(float x, float t) {
    float e = __expf(-fabsf(x));
    return fmaxf(x, 0.0f) + __logf(1.0f + e) - x * t;
}
__device__ __forceinline__ float g_f(float x, float t) {
    float e   = __expf(-fabsf(x));
    float inv = __builtin_amdgcn_rcpf(1.0f + e);
    float s   = (x >= 0.0f) ? inv : e * inv;
    return fabsf(s - t);
}
// fused fast version: one exp for both bce and g (MUST be the single shared
// definition so k_fuse and k_final produce bit-identical g)
__device__ __forceinline__ void bce_g(float x, float t, float& bce, float& g) {
    float e   = __expf(-fabsf(x));
    bce       = fmaxf(x, 0.0f) + __logf(1.0f + e) - x * t;
    float inv = __builtin_amdgcn_rcpf(1.0f + e);
    float s   = (x >= 0.0f) ? inv : e * inv;   // stable sigmoid
    g         = fabsf(s - t);
}
__device__ __forceinline__ bool col_active(const Ws* ws, int c) {
    return (ws->kdrop[c] > 0) && (ws->hardf[c] == 0);
}

// Block-wide pick (1024 threads): first bin with cumulative >= krem.
// out2[0]=bin, out2[1]=krem-prefix(bin)  (remaining count within bin, >=1).
template<int PER, int NBINS>
__device__ __forceinline__ void scan_pick(const unsigned* __restrict__ gh,
                                          unsigned krem,
                                          unsigned* wsum /*[16]*/,
                                          unsigned* out2 /*[2]*/) {
    int tid = threadIdx.x, lane = tid & 63, w = tid >> 6;
    unsigned v[PER];
    unsigned s = 0;
    #pragma unroll
    for (int i = 0; i < PER; ++i) {
        int idx = tid * PER + i;
        v[i] = (idx < NBINS) ? gh[idx] : 0u;
        s += v[i];
    }
    unsigned isc = s;
    #pragma unroll
    for (int d = 1; d < 64; d <<= 1) {
        unsigned o = __shfl_up(isc, (unsigned)d, 64);
        if (lane >= d) isc += o;
    }
    if (lane == 63) wsum[w] = isc;
    __syncthreads();
    unsigned wpre = 0;
    #pragma unroll
    for (int j = 0; j < 16; ++j) wpre += (j < w) ? wsum[j] : 0u;
    unsigned inc = wpre + isc, prev = inc - s;
    if (prev < krem && inc >= krem) {
        unsigned cum = prev;
        #pragma unroll
        for (int i = 0; i < PER; ++i) {
            if (cum < krem && cum + v[i] >= krem) {
                out2[0] = (unsigned)(tid * PER + i);
                out2[1] = krem - cum;
            }
            cum += v[i];
        }
    }
    __syncthreads();
}

// ================================================================ kernel A
// Per-column bce sum + pos count + LDS-tiled transpose of packed keys.
// XCD swizzle: XCD x writes rows [x*16384,+16384) == selection chunk x,
// so hist block (c,chunk) (bid%8==chunk) reads its 64 KB from local L2.
__global__ __launch_bounds__(640) void k_fuse(const float* __restrict__ pred,
                                              const float* __restrict__ tgt,
                                              Ws* __restrict__ ws) {
    __shared__ unsigned shk[128 * 41];   // +1 pad kills stride-40 bank conflict
    __shared__ float sl[CN];
    __shared__ int   sp[CN];
    int tid = threadIdx.x;
    if (tid < CN) { sl[tid] = 0.0f; sp[tid] = 0; }
    __syncthreads();

    int  tile  = (blockIdx.x & 7) * 128 + (blockIdx.x >> 3);   // XCD swizzle
    long tile0 = (long)tile * 5120;
    int  c0    = (tid * 4) % 40;         // fixed 4 columns per thread
    float accl[4] = {0, 0, 0, 0};
    int   cntp[4] = {0, 0, 0, 0};

    #pragma unroll
    for (int j = 0; j < 2; ++j) {
        int e = j * 2560 + tid * 4;
        const float4 p = *(const float4*)(pred + tile0 + e);
        const float4 t = *(const float4*)(tgt + tile0 + e);
        int r = e / 40;
        #pragma unroll
        for (int u = 0; u < 4; ++u) {
            float pu = (&p.x)[u], tu = (&t.x)[u];
            float bce, g;
            bce_g(pu, tu, bce, g);
            accl[u] += bce;
            int tb = (tu != 0.0f) ? 1 : 0;
            cntp[u] += tb;
            shk[r * 41 + c0 + u] = (__float_as_uint(g) << 1) | (unsigned)tb;
        }
    }
    #pragma unroll
    for (int u = 0; u < 4; ++u) {
        atomicAdd(&sl[c0 + u], accl[u]);
        atomicAdd(&sp[c0 + u], cntp[u]);
    }
    __syncthreads();

    int w = tid / 128, r = tid % 128;
    int row0 = tile * 128;
    #pragma unroll
    for (int cc = 0; cc < 8; ++cc) {
        int c = w * 8 + cc;
        ws->keys[c][row0 + r] = shk[r * 41 + c];
    }
    if (tid < CN) {
        ws->u.parts.lpart[tid][blockIdx.x] = sl[tid];
        ws->u.parts.ppart[tid][blockIdx.x] = sp[tid];
    }
}

// ================================================================ kernel PA
// 40 blocks: reduce per-block partials of one column -> lossc[c], posc[c].
__global__ __launch_bounds__(256) void k_paramsA(Ws* __restrict__ ws) {
    int c = blockIdx.x, tid = threadIdx.x;
    __shared__ double sd[256];
    __shared__ int    si[256];
    double s = 0.0; int p = 0;
    for (int i = tid; i < NBLK; i += 256) {
        s += (double)ws->u.parts.lpart[c][i];
        p += ws->u.parts.ppart[c][i];
    }
    sd[tid] = s; si[tid] = p;
    __syncthreads();
    for (int st = 128; st > 0; st >>= 1) {
        if (tid < st) { sd[tid] += sd[tid + st]; si[tid] += si[tid + st]; }
        __syncthreads();
    }
    if (tid == 0) { ws->lossc[c] = sd[0]; ws->posc[c] = si[0]; }
}

// ================================================================ kernel H0
// grid=320 (c,chunk). (1) zero my slice of u.g (ghist1/2 alias parts);
// (2) redundantly compute params from lossc/posc (chunk0 publishes);
// (3) L0 histogram: 2048 bins of mk>>19 over the chunk's majority elems.
__global__ __launch_bounds__(1024) void k_h0(const float* __restrict__ hard_rand,
                                             const float* __restrict__ pos_prop,
                                             Ws* __restrict__ ws) {
    const int bid = blockIdx.x, c = bid >> 3, chunk = bid & 7;
    const int tid = threadIdx.x;
    // zero ghist1+ghist2 region: 2*40*4096 u32 == 320*1024
    ((unsigned*)&ws->u.g)[bid * 1024 + tid] = 0;

    __shared__ double lns[CN];
    __shared__ int s_active;
    __shared__ unsigned s_majb;
    if (tid < CN) lns[tid] = log10(1.0 + ws->lossc[tid]);
    __syncthreads();
    if (tid == 0) {
        double mn = lns[0], mx = lns[0];
        for (int i = 1; i < CN; ++i) { mn = fmin(mn, lns[i]); mx = fmax(mx, lns[i]); }
        double norm = 5.0 - 10.0 * (lns[c] - mn) / (mx - mn);
        float drate = (float)(1.0 / (1.0 + exp(-norm)));   // BASE_RATE = 0
        float Bf = (float)BN;
        float pos_sum = (float)ws->posc[c];
        float neg_sum = Bf - pos_sum;
        float bal_pos = pos_prop[c] * Bf;
        float bal_neg = Bf - bal_pos;
        bool pos_gt = pos_sum > bal_pos;
        bool neg_gt = neg_sum > bal_neg;
        float balance = pos_gt ? bal_pos : (neg_gt ? bal_neg : 0.0f);
        float dnum_f  = pos_gt ? (pos_sum - bal_pos)
                               : (neg_gt ? (neg_sum - bal_neg) : 0.0f);
        int   kdrop   = (int)floorf(dnum_f);
        float majl = pos_gt ? 1.0f : 0.0f;
        float minl = neg_gt ? 1.0f : 0.0f;
        float maj_cnt = (majl == 1.0f) ? pos_sum : neg_sum;
        float min_cnt = (minl == 1.0f) ? pos_sum : neg_sum;
        int hardf = (hard_rand[c] > drate) ? 1 : 0;
        if (chunk == 0) {
            ws->drate[c]  = drate;
            ws->majl[c]   = majl;
            ws->minl[c]   = minl;
            ws->w_hard[c] = balance / fmaxf(maj_cnt, 1.0f);
            ws->w_easy[c] = (Bf - balance) / fmaxf(min_cnt, 1.0f);
            ws->hardf[c]  = hardf;
            ws->kdrop[c]  = kdrop;
            ws->minpos[c] = (min_cnt > 0.0f) ? 1 : 0;
        }
        s_active = (kdrop > 0 && hardf == 0) ? 1 : 0;
        s_majb   = (majl != 0.0f) ? 1u : 0u;
    }
    __syncthreads();
    if (!s_active) return;
    const unsigned majb = s_majb;
    const uint4* __restrict__ kc4 = (const uint4*)(ws->keys[c] + chunk * CROWS);
    __shared__ unsigned h[2048];
    h[tid] = 0; h[tid + 1024] = 0;
    __syncthreads();
    for (int b4 = tid; b4 < CROWS / 4; b4 += 1024) {
        uint4 kk = kc4[b4];
        unsigned ks[4] = {kk.x, kk.y, kk.z, kk.w};
        #pragma unroll
        for (int q = 0; q < 4; ++q)
            if ((ks[q] & 1u) == majb) atomicAdd(&h[(ks[q] >> 1) >> 19], 1u);
    }
    __syncthreads();
    if (h[tid])        atomicAdd(&ws->ghist0[c][tid], h[tid]);
    if (h[tid + 1024]) atomicAdd(&ws->ghist0[c][tid + 1024], h[tid + 1024]);
}

// ================================================================ kernel H1
// L1: filter mk>>19==p0; digit (mk>>7)&0xFFF (4096 bins).
__global__ __launch_bounds__(1024) void k_h1(Ws* __restrict__ ws) {
    int c = blockIdx.x >> 3, chunk = blockIdx.x & 7;
    if (!col_active(ws, c)) return;
    __shared__ unsigned wsum[16];
    __shared__ unsigned out2[2];
    scan_pick<2, 2048>(ws->ghist0[c], (unsigned)ws->kdrop[c], wsum, out2);
    unsigned p0 = out2[0];
    unsigned majb = (ws->majl[c] != 0.0f) ? 1u : 0u;
    const uint4* __restrict__ kc4 = (const uint4*)(ws->keys[c] + chunk * CROWS);
    __shared__ unsigned h[4096];
    int tid = threadIdx.x;
    for (int i = tid; i < 4096; i += 1024) h[i] = 0;
    __syncthreads();
    for (int b4 = tid; b4 < CROWS / 4; b4 += 1024) {
        uint4 kk = kc4[b4];
        unsigned ks[4] = {kk.x, kk.y, kk.z, kk.w};
        #pragma unroll
        for (int q = 0; q < 4; ++q)
            if ((ks[q] & 1u) == majb) {
                unsigned mk = ks[q] >> 1;
                if ((mk >> 19) == p0) atomicAdd(&h[(mk >> 7) & 0xFFFu], 1u);
            }
    }
    __syncthreads();
    for (int i = tid; i < 4096; i += 1024)
        if (h[i]) atomicAdd(&ws->u.g.h1[c][i], h[i]);
}

// ================================================================ kernel H2
// L2: filter (mk>>7)==p01; digit ((mk&0x7F)<<5)|(row>>12) (4096 bins).
__global__ __launch_bounds__(1024) void k_h2(Ws* __restrict__ ws) {
    int c = blockIdx.x >> 3, chunk = blockIdx.x & 7;
    if (!col_active(ws, c)) return;
    __shared__ unsigned wsum[16];
    __shared__ unsigned out2[2];
    scan_pick<2, 2048>(ws->ghist0[c], (unsigned)ws->kdrop[c], wsum, out2);
    unsigned p0 = out2[0], krem1 = out2[1];
    scan_pick<4, 4096>(ws->u.g.h1[c], krem1, wsum, out2);
    unsigned p01 = (p0 << 12) | out2[0];
    unsigned majb = (ws->majl[c] != 0.0f) ? 1u : 0u;
    const uint4* __restrict__ kc4 = (const uint4*)(ws->keys[c] + chunk * CROWS);
    __shared__ unsigned h[4096];
    int tid = threadIdx.x;
    for (int i = tid; i < 4096; i += 1024) h[i] = 0;
    __syncthreads();
    int rbase = chunk * CROWS;
    for (int b4 = tid; b4 < CROWS / 4; b4 += 1024) {
        uint4 kk = kc4[b4];
        unsigned ks[4] = {kk.x, kk.y, kk.z, kk.w};
        #pragma unroll
        for (int q = 0; q < 4; ++q)
            if ((ks[q] & 1u) == majb) {
                unsigned mk = ks[q] >> 1;
                if ((mk >> 7) == p01) {
                    unsigned row = (unsigned)(rbase + b4 * 4 + q);
                    atomicAdd(&h[((mk & 0x7Fu) << 5) | (row >> 12)], 1u);
                }
            }
    }
    __syncthreads();
    for (int i = tid; i < 4096; i += 1024)
        if (h[i]) atomicAdd(&ws->u.g.h2[c][i], h[i]);
}

// ================================================================ kernel T
// 40 blocks: derive (mkT,rowT). After L2 pick, candidates share mk==mkT and
// row>>12==rowHi -> scan that 4096-row band, find the krem3-th (row order).
__global__ __launch_bounds__(1024) void k_thresh(Ws* __restrict__ ws) {
    int c = blockIdx.x, tid = threadIdx.x;
    if (!col_active(ws, c)) {
        if (tid == 0) { ws->en[c] = 0; ws->mkT[c] = 0; ws->rowT[c] = 0; }
        return;
    }
    __shared__ unsigned wsum[16];
    __shared__ unsigned out2[2];
    scan_pick<2, 2048>(ws->ghist0[c], (unsigned)ws->kdrop[c], wsum, out2);
    unsigned p0 = out2[0], krem1 = out2[1];
    scan_pick<4, 4096>(ws->u.g.h1[c], krem1, wsum, out2);
    unsigned p1 = out2[0], krem2 = out2[1];
    scan_pick<4, 4096>(ws->u.g.h2[c], krem2, wsum, out2);
    unsigned p2 = out2[0], krem3 = out2[1];

    unsigned mkT = ((((p0 << 12) | p1)) << 7) | (p2 >> 5);
    unsigned rowHi = p2 & 0x1Fu;
    unsigned base = rowHi << 12;
    unsigned majb = (ws->majl[c] != 0.0f) ? 1u : 0u;
    const unsigned* __restrict__ kc = ws->keys[c];

    __shared__ unsigned wcnt[16];
    __shared__ unsigned s_row;
    int lane = tid & 63, w = tid >> 6;
    unsigned cum = 0;
    unsigned long long lanemask = (lane == 0) ? 0ull : ((~0ull) >> (64 - lane));
    for (int it = 0; it < 4; ++it) {
        unsigned row = base + it * 1024 + tid;
        unsigned key = kc[row];
        bool eq = ((key & 1u) == majb) && ((key >> 1) == mkT);
        unsigned long long bal = __ballot(eq);
        if (lane == 0) wcnt[w] = (unsigned)__popcll(bal);
        __syncthreads();
        unsigned woff = 0, tot = 0;
        for (int j = 0; j < 16; ++j) {
            unsigned v = wcnt[j];
            if (j < w) woff += v;
            tot += v;
        }
        unsigned myrank = cum + woff + (unsigned)__popcll(bal & lanemask);
        if (eq && myrank == krem3 - 1) s_row = row;
        cum += tot;
        __syncthreads();
    }
    if (tid == 0) { ws->en[c] = 1; ws->mkT[c] = mkT; ws->rowT[c] = s_row; }
}

// ================================================================ kernel F
// Final weighted sum: recompute g inline, drop test = 3 scalars/column.
// 2048 blocks x 320 threads, 64 rows/block, 6 float4 loads issued up front.
__global__ __launch_bounds__(320) void k_final4(const float* __restrict__ pred,
                                                const float* __restrict__ tgt,
                                                const float* __restrict__ rnd,
                                                Ws* __restrict__ ws,
                                                float* __restrict__ out) {
    __shared__ double sd[320];
    __shared__ float sdr[CN], smj[CN], smn[CN], swh[CN], swe[CN];
    __shared__ int shf[CN], smp[CN], sen[CN];
    __shared__ unsigned skT[CN], srT[CN];
    int tid = threadIdx.x;
    if (tid < CN) {
        sdr[tid] = ws->drate[tid]; smj[tid] = ws->majl[tid];
        smn[tid] = ws->minl[tid];  swh[tid] = ws->w_hard[tid];
        swe[tid] = ws->w_easy[tid]; shf[tid] = ws->hardf[tid];
        smp[tid] = ws->minpos[tid]; sen[tid] = ws->en[tid];
        skT[tid] = ws->mkT[tid];   srT[tid] = ws->rowT[tid];
    }
    __syncthreads();

    long i0 = (long)blockIdx.x * 2560 + tid * 4;
    const float4 pA = *(const float4*)(pred + i0);
    const float4 tA = *(const float4*)(tgt + i0);
    const float4 rA = *(const float4*)(rnd + i0);
    const float4 pB = *(const float4*)(pred + i0 + 1280);
    const float4 tB = *(const float4*)(tgt + i0 + 1280);
    const float4 rB = *(const float4*)(rnd + i0 + 1280);

    int c0 = (tid * 4) % 40;
    unsigned b0 = (unsigned)(i0 / 40);
    float drate[4], majl[4], minl[4], wh[4], we[4];
    int hf[4], mp[4], en[4];
    unsigned mkT[4], rowT[4];
    #pragma unroll
    for (int u = 0; u < 4; ++u) {
        int c = c0 + u;
        drate[u] = sdr[c]; majl[u] = smj[c]; minl[u] = smn[c];
        wh[u] = swh[c]; we[u] = swe[c];
        hf[u] = shf[c]; mp[u] = smp[c]; en[u] = sen[c];
        mkT[u] = skT[c]; rowT[u] = srT[c];
    }
    double acc = 0.0;
    #pragma unroll
    for (int j = 0; j < 2; ++j) {
        const float4& p = j ? pB : pA;
        const float4& t = j ? tB : tA;
        const float4& r = j ? rB : rA;
        unsigned b = b0 + (j ? 32u : 0u);
        #pragma unroll
        for (int u = 0; u < 4; ++u) {
            float pu = (&p.x)[u], tu = (&t.x)[u], ru = (&r.x)[u];
            float bce, g;
            bce_g(pu, tu, bce, g);
            float w;
            if (hf[u]) {
                w = (tu == majl[u]) ? wh[u] : 1.0f;
            } else {
                unsigned mk = __float_as_uint(g);
                bool dropped = (tu == majl[u]) && en[u] &&
                               (mk < mkT[u] || (mk == mkT[u] && b <= rowT[u]));
                w = dropped ? 0.0f : ((tu == minl[u] && mp[u]) ? we[u] : 1.0f);
            }
            if (g >= 0.8f && g < 1.000001f && ru > drate[u]) w = 0.0f;
            acc += (double)(bce * w);
        }
    }
    sd[tid] = acc;
    __syncthreads();
    for (int s = 160; s >= 5; s >>= 1) {
        if (tid < s) sd[tid] += sd[tid + s];
        __syncthreads();
    }
    if (tid == 0) {
        double v = sd[0] + sd[1] + sd[2] + sd[3] + sd[4];
        atomicAdd(&ws->acc, v);
        __threadfence();
        unsigned t = atomicAdd(&ws->done, 1u);
        if (t == (unsigned)(NFIN - 1)) {
            double total = atomicAdd(&ws->acc, 0.0);   // coherent read
            out[0] = (float)(total / (double)NTOT);
        }
    }
}

// ================================================================ round-1
// fallback (ws too small)
__global__ void k_colreduce(const float* __restrict__ pred,
                            const float* __restrict__ tgt,
                            Ws* __restrict__ ws) {
    __shared__ float sl[CN];
    __shared__ int   sp[CN];
    int tid = threadIdx.x;
    if (tid < CN) { sl[tid] = 0.0f; sp[tid] = 0; }
    __syncthreads();
    int stride = gridDim.x * blockDim.x;
    for (int i = blockIdx.x * blockDim.x + tid; i < NTOT; i += stride) {
        int c = i % CN;
        float p = pred[i], t = tgt[i];
        atomicAdd(&sl[c], bce_f(p, t));
        if (t != 0.0f) atomicAdd(&sp[c], 1);
    }
    __syncthreads();
    if (tid < CN) {
        atomicAdd(&ws->lossc[tid], (double)sl[tid]);
        atomicAdd(&ws->posc[tid], sp[tid]);
    }
}

__global__ __launch_bounds__(1024) void k_params(const float* __restrict__ hard_rand,
                                                 const float* __restrict__ pos_prop,
                                                 Ws* __restrict__ ws) {
    int tid = threadIdx.x;
    __shared__ double lns[CN];
    __shared__ double smn, smx;
    if (tid < CN) lns[tid] = log10(1.0 + ws->lossc[tid]);
    __syncthreads();
    if (tid == 0) {
        double a = lns[0], b = lns[0];
        for (int i = 1; i < CN; i++) { a = fmin(a, lns[i]); b = fmax(b, lns[i]); }
        smn = a; smx = b;
    }
    __syncthreads();
    if (tid < CN) {
        int c = tid;
        double norm = 5.0 - 10.0 * (lns[c] - smn) / (smx - smn);
        float drate = (float)(1.0 / (1.0 + exp(-norm)));
        float Bf = (float)BN;
        float pos_sum = (float)ws->posc[c];
        float neg_sum = Bf - pos_sum;
        float bal_pos = pos_prop[c] * Bf;
        float bal_neg = Bf - bal_pos;
        bool pos_gt = pos_sum > bal_pos;
        bool neg_gt = neg_sum > bal_neg;
        float balance = pos_gt ? bal_pos : (neg_gt ? bal_neg : 0.0f);
        float dnum_f  = pos_gt ? (pos_sum - bal_pos)
                               : (neg_gt ? (neg_sum - bal_neg) : 0.0f);
        int   kdrop   = (int)floorf(dnum_f);
        float majl = pos_gt ? 1.0f : 0.0f;
        float minl = neg_gt ? 1.0f : 0.0f;
        float maj_cnt = (majl == 1.0f) ? pos_sum : neg_sum;
        float min_cnt = (minl == 1.0f) ? pos_sum : neg_sum;
        ws->drate[c]  = drate;
        ws->majl[c]   = majl;
        ws->minl[c]   = minl;
        ws->w_hard[c] = balance / fmaxf(maj_cnt, 1.0f);
        ws->w_easy[c] = (Bf - balance) / fmaxf(min_cnt, 1.0f);
        ws->hardf[c]  = (hard_rand[c] > drate) ? 1 : 0;
        ws->kdrop[c]  = kdrop;
        ws->minpos[c] = (min_cnt > 0.0f) ? 1 : 0;
    }
}

__global__ __launch_bounds__(1024) void k_select(const float* __restrict__ pred,
                                                 const float* __restrict__ tgt,
                                                 Ws* __restrict__ ws) {
    int c   = blockIdx.x;
    int tid = threadIdx.x;
    int k   = ws->kdrop[c];
    bool easy = (ws->hardf[c] == 0);
    unsigned long long* mrow = ws->u.mask[c];
    if (k <= 0 || !easy) {
        for (int i = tid; i < MASKW; i += 1024) mrow[i] = 0ull;
        return;
    }
    float majl = ws->majl[c];
    __shared__ unsigned h[256];
    __shared__ unsigned cum[256];
    __shared__ unsigned sh_sel, sh_krem;
    unsigned prefix = 0;
    unsigned krem   = (unsigned)k;
    for (int level = 0; level < 4; ++level) {
        int shift = 24 - 8 * level;
        for (int i = tid; i < 256; i += 1024) h[i] = 0;
        __syncthreads();
        for (int b = tid; b < BN; b += 1024) {
            float t = tgt[b * CN + c];
            if (t == majl) {
                unsigned bits = __float_as_uint(g_f(pred[b * CN + c], t));
                bool ok = (level == 0) || ((bits >> (shift + 8)) == prefix);
                if (ok) atomicAdd(&h[(bits >> shift) & 0xFFu], 1u);
            }
        }
        __syncthreads();
        if (tid < 256) cum[tid] = h[tid];
        __syncthreads();
        for (int off = 1; off < 256; off <<= 1) {
            unsigned v = 0;
            if (tid < 256 && tid >= off) v = cum[tid - off];
            __syncthreads();
            if (tid < 256 && tid >= off) cum[tid] += v;
            __syncthreads();
        }
        if (tid < 256) {
            unsigned prev = (tid == 0) ? 0u : cum[tid - 1];
            if (cum[tid] >= krem && prev < krem) {
                sh_sel  = (unsigned)tid;
                sh_krem = krem - prev;
            }
        }
        __syncthreads();
        prefix = (prefix << 8) | sh_sel;
        krem   = sh_krem;
        __syncthreads();
    }
    unsigned T    = prefix;
    unsigned need = krem;
    __shared__ unsigned wcnt[16];
    unsigned base = 0;
    int lane = tid & 63, wid = tid >> 6;
    for (int chunk = 0; chunk < BN / 1024; ++chunk) {
        int b = chunk * 1024 + tid;
        float t = tgt[b * CN + c];
        bool ismaj = (t == majl);
        unsigned bits = 0xFFFFFFFFu;
        if (ismaj) bits = __float_as_uint(g_f(pred[b * CN + c], t));
        bool lt = ismaj && (bits < T);
        bool eq = ismaj && (bits == T);
        unsigned long long bal = __ballot(eq);
        if (lane == 0) wcnt[wid] = (unsigned)__popcll(bal);
        __syncthreads();
        unsigned woff = 0, tot = 0;
        for (int w = 0; w < 16; ++w) {
            unsigned v = wcnt[w];
            if (w < wid) woff += v;
            tot += v;
        }
        unsigned long long lanemask = (lane == 0) ? 0ull : ((~0ull) >> (64 - lane));
        unsigned myrank = base + woff + (unsigned)__popcll(bal & lanemask);
        bool dropped = lt || (eq && myrank < need);
        unsigned long long bd = __ballot(dropped);
        if (lane == 0) mrow[chunk * 16 + wid] = bd;
        base += tot;
        __syncthreads();
    }
}

__global__ void k_final(const float* __restrict__ pred,
                        const float* __restrict__ tgt,
                        const float* __restrict__ rnd,
                        Ws* __restrict__ ws) {
    __shared__ double sdata[256];
    double acc = 0.0;
    int stride = gridDim.x * blockDim.x;
    for (int i = blockIdx.x * blockDim.x + threadIdx.x; i < NTOT; i += stride) {
        int b = i / CN;
        int c = i - b * CN;
        float p = pred[i], t = tgt[i], r = rnd[i];
        float bce = bce_f(p, t);
        float g   = g_f(p, t);
        float w;
        if (ws->hardf[c]) {
            w = (t == ws->majl[c]) ? ws->w_hard[c] : 1.0f;
        } else {
            bool dropped = (ws->u.mask[c][b >> 6] >> (b & 63)) & 1ull;
            if (dropped) w = 0.0f;
            else w = ((t == ws->minl[c]) && ws->minpos[c]) ? ws->w_easy[c] : 1.0f;
        }
        if ((g >= 0.8f) && (g < 1.000001f) && (r > ws->drate[c])) w = 0.0f;
        acc += (double)(bce * w);
    }
    sdata[threadIdx.x] = acc;
    __syncthreads();
    for (int s = blockDim.x / 2; s > 0; s >>= 1) {
        if (threadIdx.x < s) sdata[threadIdx.x] += sdata[threadIdx.x + s];
        __syncthreads();
    }
    if (threadIdx.x == 0) atomicAdd(&ws->acc, sdata[0]);
}

__global__ void k_write(Ws* __restrict__ ws, float* __restrict__ out) {
    out[0] = (float)(ws->acc / (double)NTOT);
}

extern "C" void kernel_launch(void* const* d_in, const int* in_sizes, int n_in,
                              void* d_out, int out_size, void* d_ws, size_t ws_size,
                              hipStream_t stream) {
    const float* pred      = (const float*)d_in[0];
    const float* tgt       = (const float*)d_in[1];
    const float* rnd       = (const float*)d_in[2];
    const float* hard_rand = (const float*)d_in[3];
    const float* pos_prop  = (const float*)d_in[4];
    Ws* ws = (Ws*)d_ws;

    if (ws_size >= sizeof(Ws)) {
        hipMemsetAsync(d_ws, 0, offsetof(Ws, u), stream);   // acc+done+ghist0
        k_fuse   <<<NBLK, 640, 0, stream>>>(pred, tgt, ws);
        k_paramsA<<<CN, 256, 0, stream>>>(ws);
        k_h0     <<<CN * NCHUNK, 1024, 0, stream>>>(hard_rand, pos_prop, ws);
        k_h1     <<<CN * NCHUNK, 1024, 0, stream>>>(ws);
        k_h2     <<<CN * NCHUNK, 1024, 0, stream>>>(ws);
        k_thresh <<<CN, 1024, 0, stream>>>(ws);
        k_final4 <<<NFIN, 320, 0, stream>>>(pred, tgt, rnd, ws, (float*)d_out);
    } else {
        hipMemsetAsync(d_ws, 0, offsetof(Ws, u), stream);
        hipMemsetAsync(&((Ws*)d_ws)->lossc, 0, sizeof(double) * CN + sizeof(int) * CN, stream);
        k_colreduce<<<2048, 256, 0, stream>>>(pred, tgt, ws);
        k_params<<<1, 1024, 0, stream>>>(hard_rand, pos_prop, ws);
        k_select<<<CN, 1024, 0, stream>>>(pred, tgt, ws);
        k_final <<<2048, 256, 0, stream>>>(pred, tgt, rnd, ws);
        k_write <<<1, 1, 0, stream>>>(ws, (float*)d_out);
    }
}